// Round 10
// baseline (732.272 us; speedup 1.0000x reference)
//
#include <hip/hip_runtime.h>
#include <hip/hip_bf16.h>

#define N_NODES 10000
#define E_EDGES 160000
#define ETOT    170000   // E + N self loops
#define H_HEADS 8
#define C_CH    128
#define D_DIM   1024
#define NBLK    3
#define NGRAPH  64
#define NEG_SLOPE 0.2f
#define BN_EPS  1e-5f

#define MTILES  157      // ceil(10000/64)
#define MGRP    40       // ceil(157/4) m-tiles per block-group of 4 waves

typedef __attribute__((ext_vector_type(8))) _Float16 half8;
typedef __attribute__((ext_vector_type(4))) _Float16 half4;
typedef __attribute__((ext_vector_type(2))) _Float16 half2v;
typedef __attribute__((ext_vector_type(4))) float f32x4;

// first index i in sorted batch[0..N) with batch[i] >= g
__device__ inline int lower_bound_batch(const int* __restrict__ batch, int g) {
    int lo = 0, hi = N_NODES;
    while (lo < hi) {
        int mid = (lo + hi) >> 1;
        if (batch[mid] < g) lo = mid + 1;
        else hi = mid;
    }
    return lo;
}

// ---------------- CSR build ----------------
__global__ void deg_kernel(const int* __restrict__ ei, int* __restrict__ deg) {
    int tid = blockIdx.x * blockDim.x + threadIdx.x;
    if (tid >= ETOT) return;
    int dst = (tid < E_EDGES) ? ei[E_EDGES + tid] : (tid - E_EDGES);
    atomicAdd(&deg[dst], 1);
}

__global__ void scan_kernel(const int* __restrict__ deg, int* __restrict__ ioff) {
    __shared__ int part[256];
    int t = threadIdx.x;
    const int CH = (N_NODES + 255) / 256; // 40
    int base = t * CH;
    int s = 0;
    for (int j = 0; j < CH; ++j) {
        int idx = base + j;
        if (idx < N_NODES) s += deg[idx];
    }
    part[t] = s;
    __syncthreads();
    for (int o = 1; o < 256; o <<= 1) {
        int v = 0;
        if (t >= o) v = part[t - o];
        __syncthreads();
        part[t] += v;
        __syncthreads();
    }
    int run = (t == 0) ? 0 : part[t - 1];
    for (int j = 0; j < CH; ++j) {
        int idx = base + j;
        if (idx < N_NODES) { ioff[idx] = run; run += deg[idx]; }
    }
}

__global__ void scatter_kernel(const int* __restrict__ ei, int* __restrict__ ioff,
                               int* __restrict__ csr_src) {
    int tid = blockIdx.x * blockDim.x + threadIdx.x;
    if (tid >= ETOT) return;
    int src, dst;
    if (tid < E_EDGES) { src = ei[tid]; dst = ei[E_EDGES + tid]; }
    else { src = dst = tid - E_EDGES; }
    int pos = atomicAdd(&ioff[dst], 1);
    csr_src[pos] = src;
}

// ---------------- x -> fp16 ----------------
__global__ __launch_bounds__(256) void xconv_kernel(const float* __restrict__ in,
                                                    _Float16* __restrict__ o, int n4) {
    int i = blockIdx.x * blockDim.x + threadIdx.x;
    if (i >= n4) return;
    float4 v = ((const float4*)in)[i];
    half4 h = {(_Float16)v.x, (_Float16)v.y, (_Float16)v.z, (_Float16)v.w};
    ((half4*)o)[i] = h;
}

// W [k][n] fp32 -> Wt [n][k] fp16 (transposed); blockIdx.z = layer
__global__ __launch_bounds__(256) void wtconv_kernel(const float* __restrict__ Wall,
                                                     _Float16* __restrict__ t16all) {
    const float* W = Wall + (size_t)blockIdx.z * D_DIM * D_DIM;
    _Float16* t16 = t16all + (size_t)blockIdx.z * D_DIM * D_DIM;
    __shared__ float t[32][33];
    int bn = blockIdx.x * 32;
    int bk = blockIdx.y * 32;
    int tx = threadIdx.x & 31;
    int ty = threadIdx.x >> 5;
#pragma unroll
    for (int r = 0; r < 32; r += 8)
        t[ty + r][tx] = W[(size_t)(bk + ty + r) * D_DIM + bn + tx];
    __syncthreads();
#pragma unroll
    for (int r = 0; r < 32; r += 8)
        t16[(size_t)(bn + ty + r) * D_DIM + bk + tx] = (_Float16)t[tx][ty + r];
}

// ---------------- fp16 MFMA GEMM, barrier-free independent waves ----------------
// Each wave owns a 64(m) x 128(n = one head) tile and a private 12 KB LDS
// quadrant: stages A (4 KB) + B (8 KB) per kb via global_load_lds (dest =
// wave-uniform base + lane*16), then ds_read + 32 MFMA. No __syncthreads at
// all — the only wait is the wave's own vmcnt, so resident waves overlap
// freely (R8/R9 were a barrier-serialized latency chain: 1 block/CU active,
// MfmaUtil 12%). head = bx&7 keeps B-slice + Hout XCD-local; group-major
// order co-sweeps A across the 8 head-streams for L3 reuse.
// Epilogue: full head in-wave -> att-logit dots need no LDS/atomic combine.
__global__ __launch_bounds__(256) void gemm_mfma_kernel(const _Float16* __restrict__ A,
                                                        const _Float16* __restrict__ Bt,
                                                        _Float16* __restrict__ Hout,
                                                        const float* __restrict__ att_s,
                                                        const float* __restrict__ att_d,
                                                        float* __restrict__ asrc,
                                                        float* __restrict__ adst, int M) {
    __shared__ short As[4][64 * 32];   // per-wave [m][k]
    __shared__ short Bs[4][128 * 32];  // per-wave [n][k]
    int bx = blockIdx.x;
    int head = bx & 7;
    int grp = bx >> 3;
    int tid = threadIdx.x;
    int wave = tid >> 6;
    int lane = tid & 63;
    int mt = grp * 4 + wave;           // 0..159 (157..159 are padding)
    int bm = mt * 64;
    int bn = head * 128;
    int quad = lane >> 4;
    int l16 = lane & 15;

    short* Asw = As[wave];
    short* Bsw = Bs[wave];

    f32x4 acc[4][8];
#pragma unroll
    for (int ii = 0; ii < 4; ++ii)
#pragma unroll
        for (int j = 0; j < 8; ++j) acc[ii][j] = (f32x4){0.f, 0.f, 0.f, 0.f};

    int srow = lane >> 2;        // 0..15
    int scol = (lane & 3) * 16;  // byte offset in 64-byte k-row

    for (int kb = 0; kb < 32; ++kb) {
        int k0 = kb * 32;
        // stage A: 64 rows x 32 k (4 KB), 4 rounds of 16 rows
#pragma unroll
        for (int r = 0; r < 4; ++r) {
            int grow = bm + r * 16 + srow;
            if (grow > M - 1) grow = M - 1;
            const char* gp = (const char*)(A + (size_t)grow * 1024 + k0) + scol;
            __builtin_amdgcn_global_load_lds(
                (const __attribute__((address_space(1))) void*)gp,
                (__attribute__((address_space(3))) void*)((char*)Asw + (r * 16) * 64),
                16, 0, 0);
        }
        // stage B: 128 rows x 32 k (8 KB), 8 rounds
#pragma unroll
        for (int r = 0; r < 8; ++r) {
            int brow = bn + r * 16 + srow;
            const char* gp = (const char*)(Bt + (size_t)brow * 1024 + k0) + scol;
            __builtin_amdgcn_global_load_lds(
                (const __attribute__((address_space(1))) void*)gp,
                (__attribute__((address_space(3))) void*)((char*)Bsw + (r * 16) * 64),
                16, 0, 0);
        }
        // compiler inserts per-wave s_waitcnt vmcnt(0) before first ds_read
        half8 af[4], bfr[8];
#pragma unroll
        for (int ii = 0; ii < 4; ++ii)
            af[ii] = *(const half8*)(Asw + (ii * 16 + l16) * 32 + quad * 8);
#pragma unroll
        for (int j = 0; j < 8; ++j)
            bfr[j] = *(const half8*)(Bsw + (j * 16 + l16) * 32 + quad * 8);
#pragma unroll
        for (int ii = 0; ii < 4; ++ii)
#pragma unroll
            for (int j = 0; j < 8; ++j)
                acc[ii][j] = __builtin_amdgcn_mfma_f32_16x16x32_f16(af[ii], bfr[j], acc[ii][j], 0, 0, 0);
    }

    // attention-logit dots over the full head (128 cols, all in this wave)
    float wsv[8], wdv[8];
#pragma unroll
    for (int j = 0; j < 8; ++j) {
        int c = j * 16 + l16;
        wsv[j] = att_s[head * 128 + c];
        wdv[j] = att_d[head * 128 + c];
    }
#pragma unroll
    for (int ii = 0; ii < 4; ++ii) {
#pragma unroll
        for (int reg = 0; reg < 4; ++reg) {
            float p = 0.f, q = 0.f;
#pragma unroll
            for (int j = 0; j < 8; ++j) {
                p = fmaf(acc[ii][j][reg], wsv[j], p);
                q = fmaf(acc[ii][j][reg], wdv[j], q);
            }
#pragma unroll
            for (int o = 1; o < 16; o <<= 1) {
                p += __shfl_xor(p, o);
                q += __shfl_xor(q, o);
            }
            int gr = bm + ii * 16 + quad * 4 + reg;
            if (l16 == 0 && gr < M) {
                asrc[gr * 8 + head] = p;
                adst[gr * 8 + head] = q;
            }
        }
    }
    // store h fp16, head-major (C/D layout: col=lane&15, row=quad*4+reg)
#pragma unroll
    for (int ii = 0; ii < 4; ++ii) {
#pragma unroll
        for (int reg = 0; reg < 4; ++reg) {
            int gr = bm + ii * 16 + quad * 4 + reg;
            if (gr < M) {
                _Float16* hp = Hout + (size_t)head * N_NODES * 128 + (size_t)gr * 128 + l16;
#pragma unroll
                for (int j = 0; j < 8; ++j) hp[j * 16] = (_Float16)acc[ii][j][reg];
            }
        }
    }
}

// ---------------- fused edge-softmax aggregation, head-partitioned ----------------
__global__ __launch_bounds__(256) void agg_kernel(const _Float16* __restrict__ h16,
                                                  const float* __restrict__ asrc,
                                                  const float* __restrict__ adst,
                                                  const int* __restrict__ ioff,
                                                  const int* __restrict__ csr_src,
                                                  const _Float16* __restrict__ prevh,
                                                  const float* __restrict__ bias,
                                                  _Float16* __restrict__ yout,
                                                  float* __restrict__ stats) {
    int bx = blockIdx.x;
    int tid = threadIdx.x;
    if (bx == 0) {
#pragma unroll
        for (int j = 0; j < 8; ++j) stats[tid + j * 256] = 0.f;
    }
    int head = bx & 7;
    int chunk = bx >> 3;
    int sub = tid >> 5;
    int lane = tid & 31;
    int n = chunk * 8 + sub;          // N=10000 divisible by 8
    int c4 = lane * 4;
    const _Float16* hh = h16 + (size_t)head * N_NODES * 128;
    int start = (n == 0) ? 0 : ioff[n - 1];
    int end = ioff[n];
    float ad = adst[n * 8 + head];
    float den = 0.f;
    float4 acc = make_float4(0.f, 0.f, 0.f, 0.f);
    int p = start;
    for (; p + 4 <= end; p += 4) {
        int s0 = csr_src[p + 0];
        int s1 = csr_src[p + 1];
        int s2 = csr_src[p + 2];
        int s3 = csr_src[p + 3];
        float a0 = asrc[s0 * 8 + head];
        float a1 = asrc[s1 * 8 + head];
        float a2 = asrc[s2 * 8 + head];
        float a3 = asrc[s3 * 8 + head];
        half4 h0 = *(const half4*)(hh + (size_t)s0 * 128 + c4);
        half4 h1 = *(const half4*)(hh + (size_t)s1 * 128 + c4);
        half4 h2 = *(const half4*)(hh + (size_t)s2 * 128 + c4);
        half4 h3 = *(const half4*)(hh + (size_t)s3 * 128 + c4);
        float e0 = a0 + ad; e0 = (e0 > 0.f) ? e0 : NEG_SLOPE * e0;
        float e1 = a1 + ad; e1 = (e1 > 0.f) ? e1 : NEG_SLOPE * e1;
        float e2 = a2 + ad; e2 = (e2 > 0.f) ? e2 : NEG_SLOPE * e2;
        float e3 = a3 + ad; e3 = (e3 > 0.f) ? e3 : NEG_SLOPE * e3;
        float x0 = __expf(e0), x1 = __expf(e1), x2 = __expf(e2), x3 = __expf(e3);
        den += (x0 + x1) + (x2 + x3);
        acc.x += x0 * (float)h0[0] + x1 * (float)h1[0] + x2 * (float)h2[0] + x3 * (float)h3[0];
        acc.y += x0 * (float)h0[1] + x1 * (float)h1[1] + x2 * (float)h2[1] + x3 * (float)h3[1];
        acc.z += x0 * (float)h0[2] + x1 * (float)h1[2] + x2 * (float)h2[2] + x3 * (float)h3[2];
        acc.w += x0 * (float)h0[3] + x1 * (float)h1[3] + x2 * (float)h2[3] + x3 * (float)h3[3];
    }
    for (; p < end; ++p) {
        int s = csr_src[p];
        float e = asrc[s * 8 + head] + ad;
        e = (e > 0.f) ? e : NEG_SLOPE * e;
        float ex = __expf(e);
        den += ex;
        half4 hv = *(const half4*)(hh + (size_t)s * 128 + c4);
        acc.x = fmaf(ex, (float)hv[0], acc.x);
        acc.y = fmaf(ex, (float)hv[1], acc.y);
        acc.z = fmaf(ex, (float)hv[2], acc.z);
        acc.w = fmaf(ex, (float)hv[3], acc.w);
    }
    float invd = 1.0f / den;
    int col = head * 128 + c4;
    half4 ph = *(const half4*)(prevh + (size_t)n * 1024 + col);
    float4 bv = *(const float4*)(bias + col);
    float r0 = fmaf(acc.x, invd, (float)ph[0] + bv.x);
    float r1 = fmaf(acc.y, invd, (float)ph[1] + bv.y);
    float r2 = fmaf(acc.z, invd, (float)ph[2] + bv.z);
    float r3 = fmaf(acc.w, invd, (float)ph[3] + bv.w);
    half4 o = {(_Float16)r0, (_Float16)r1, (_Float16)r2, (_Float16)r3};
    *(half4*)(yout + (size_t)n * 1024 + col) = o;
}

// ---------------- batchnorm (fp16 y) ----------------
__global__ void bn_stats_kernel(const _Float16* __restrict__ y, float* __restrict__ stats) {
    int col = (blockIdx.x * 256 + threadIdx.x) * 2;  // grid.x = 2
    float s0 = 0.f, s1 = 0.f, q0 = 0.f, q1 = 0.f;
    for (int r = blockIdx.y; r < N_NODES; r += gridDim.y) {
        half2v v = *(const half2v*)(y + (size_t)r * 1024 + col);
        float a = (float)v[0], b = (float)v[1];
        s0 += a; q0 += a * a;
        s1 += b; q1 += b * b;
    }
    atomicAdd(&stats[col], s0);
    atomicAdd(&stats[col + 1], s1);
    atomicAdd(&stats[1024 + col], q0);
    atomicAdd(&stats[1024 + col + 1], q1);
}

// normalize+relu: y16 -> o16 (o is next layer's GEMM A / prev / pool input)
__global__ void bn_apply_kernel(const _Float16* __restrict__ y, const float* __restrict__ stats,
                                const float* __restrict__ gamma, const float* __restrict__ beta,
                                _Float16* __restrict__ oout) {
    int idx4 = blockIdx.x * blockDim.x + threadIdx.x;
    if (idx4 >= N_NODES * D_DIM / 4) return;
    int base = idx4 * 4;
    int col = base & 1023;
    const float invN = 1.0f / (float)N_NODES;
    half4 v = ((const half4*)y)[idx4];
    float r[4];
#pragma unroll
    for (int j = 0; j < 4; ++j) {
        int cc = col + j;
        float mu = stats[cc] * invN;
        float var = stats[1024 + cc] * invN - mu * mu;
        float t = ((float)v[j] - mu) * rsqrtf(var + BN_EPS) * gamma[cc] + beta[cc];
        r[j] = fmaxf(t, 0.f);
    }
    half4 h = {(_Float16)r[0], (_Float16)r[1], (_Float16)r[2], (_Float16)r[3]};
    ((half4*)oout)[idx4] = h;
}

// ---------------- pooling (atomic-free) + final linear ----------------
__global__ __launch_bounds__(256) void pool_kernel(const _Float16* __restrict__ h3,
                                                   const int* __restrict__ batch,
                                                   float* __restrict__ pooled) {
    int col = blockIdx.x * 256 + threadIdx.x;   // grid.x = 4
    int g = blockIdx.y;
    int lo = lower_bound_batch(batch, g);
    int hi = lower_bound_batch(batch, g + 1);
    float acc = 0.f;
    for (int r = lo; r < hi; ++r) acc += (float)h3[(size_t)r * 1024 + col];
    pooled[(size_t)g * 1024 + col] = acc;
}

__global__ void final_kernel(const float* __restrict__ pooled, const int* __restrict__ batch,
                             const float* __restrict__ Wout, const float* __restrict__ bout,
                             float* __restrict__ out) {
    int g = blockIdx.x;
    int t = threadIdx.x;
    float p0 = 0.f, p1 = 0.f;
    for (int d = t; d < 1024; d += 256) {
        float v = pooled[(size_t)g * 1024 + d];
        p0 = fmaf(v, Wout[2 * d], p0);
        p1 = fmaf(v, Wout[2 * d + 1], p1);
    }
    __shared__ float s0[256], s1[256];
    s0[t] = p0; s1[t] = p1;
    __syncthreads();
    for (int o = 128; o; o >>= 1) {
        if (t < o) { s0[t] += s0[t + o]; s1[t] += s1[t + o]; }
        __syncthreads();
    }
    if (t == 0) {
        int cnt = lower_bound_batch(batch, g + 1) - lower_bound_batch(batch, g);
        float inv = 1.0f / fmaxf((float)cnt, 1.0f);
        out[g * 2 + 0] = s0[0] * inv + bout[0];
        out[g * 2 + 1] = s1[0] * inv + bout[1];
    }
}

extern "C" void kernel_launch(void* const* d_in, const int* in_sizes, int n_in,
                              void* d_out, int out_size, void* d_ws, size_t ws_size,
                              hipStream_t stream) {
    const float* x        = (const float*)d_in[0];
    const int*   ei       = (const int*)d_in[1];
    const int*   batch    = (const int*)d_in[2];
    const float* W        = (const float*)d_in[3];
    const float* att_src  = (const float*)d_in[4];
    const float* att_dst  = (const float*)d_in[5];
    const float* att_bias = (const float*)d_in[6];
    const float* gamma    = (const float*)d_in[7];
    const float* beta     = (const float*)d_in[8];
    const float* Wout     = (const float*)d_in[9];
    const float* bout     = (const float*)d_in[10];
    float* out = (float*)d_out;

    const size_t ND = (size_t)N_NODES * D_DIM;
    float* ws = (float*)d_ws;
    float* asrc   = ws;                                  // N*H
    float* adst   = asrc + (size_t)N_NODES * H_HEADS;    // N*H
    float* stats  = adst + (size_t)N_NODES * H_HEADS;    // 2*D
    float* pooled = stats + 2 * D_DIM;                   // NG*D
    int* ideg     = (int*)(pooled + (size_t)NGRAPH * D_DIM); // N
    int* ioff     = ideg + N_NODES;                      // N
    int* csr_src  = ioff + N_NODES;                      // ETOT
    _Float16* bufP  = (_Float16*)(csr_src + ETOT);       // N*D: x16 -> o1 -> o2
    _Float16* bufO0 = bufP + ND;                         // N*D: o0
    _Float16* h16   = bufO0 + ND;                        // N*D: GEMM out, [8][N][128]
    _Float16* y16   = h16 + ND;                          // N*D: agg out (pre-BN)
    _Float16* Wt3   = y16 + ND;                          // 3*D*D fp16 (W^T)
    // total ≈ 93 MB

    hipMemsetAsync(ideg, 0, N_NODES * sizeof(int), stream);
    deg_kernel<<<(ETOT + 255) / 256, 256, 0, stream>>>(ei, ideg);
    scan_kernel<<<1, 256, 0, stream>>>(ideg, ioff);
    scatter_kernel<<<(ETOT + 255) / 256, 256, 0, stream>>>(ei, ioff, csr_src);
    xconv_kernel<<<(int)(ND / 4 + 255) / 256, 256, 0, stream>>>(x, bufP, (int)(ND / 4));
    wtconv_kernel<<<dim3(32, 32, 3), 256, 0, stream>>>(W, Wt3);

    // layer i: A = Ain[i]; prev = Pin[i] (all fp16); bn output -> Oout[i]
    const _Float16* Ain[3]  = {bufP, bufO0, bufP};
    const _Float16* Pin[3]  = {bufP, bufP, bufO0};
    _Float16* Oout[3]       = {bufO0, bufP, bufP};

    for (int i = 0; i < NBLK; ++i) {
        gemm_mfma_kernel<<<MGRP * 8, 256, 0, stream>>>(
            Ain[i], Wt3 + (size_t)i * D_DIM * D_DIM, h16,
            att_src + i * H_HEADS * C_CH, att_dst + i * H_HEADS * C_CH,
            asrc, adst, N_NODES);
        agg_kernel<<<N_NODES, 256, 0, stream>>>(h16, asrc, adst, ioff, csr_src,
                                                Pin[i], att_bias + i * D_DIM, y16, stats);
        bn_stats_kernel<<<dim3(2, 128), 256, 0, stream>>>(y16, stats);
        bn_apply_kernel<<<(int)(ND / 4 + 255) / 256, 256, 0, stream>>>(
            y16, stats, gamma + i * D_DIM, beta + i * D_DIM, Oout[i]);
    }

    pool_kernel<<<dim3(4, NGRAPH), 256, 0, stream>>>(bufP, batch, pooled);
    final_kernel<<<NGRAPH, 256, 0, stream>>>(pooled, batch, Wout, bout, out);
}

// Round 12
// 624.984 us; speedup vs baseline: 1.1717x; 1.1717x over previous
//
#include <hip/hip_runtime.h>
#include <hip/hip_bf16.h>

#define N_NODES 10000
#define E_EDGES 160000
#define ETOT    170000   // E + N self loops
#define H_HEADS 8
#define C_CH    128
#define D_DIM   1024
#define NBLK    3
#define NGRAPH  64
#define NEG_SLOPE 0.2f
#define BN_EPS  1e-5f

typedef __attribute__((ext_vector_type(8))) _Float16 half8;
typedef __attribute__((ext_vector_type(4))) _Float16 half4;
typedef __attribute__((ext_vector_type(2))) _Float16 half2v;
typedef __attribute__((ext_vector_type(4))) float f32x4;

// first index i in sorted batch[0..N) with batch[i] >= g
__device__ inline int lower_bound_batch(const int* __restrict__ batch, int g) {
    int lo = 0, hi = N_NODES;
    while (lo < hi) {
        int mid = (lo + hi) >> 1;
        if (batch[mid] < g) lo = mid + 1;
        else hi = mid;
    }
    return lo;
}

// ---------------- CSR build ----------------
__global__ void deg_kernel(const int* __restrict__ ei, int* __restrict__ deg) {
    int tid = blockIdx.x * blockDim.x + threadIdx.x;
    if (tid >= ETOT) return;
    int dst = (tid < E_EDGES) ? ei[E_EDGES + tid] : (tid - E_EDGES);
    atomicAdd(&deg[dst], 1);
}

__global__ void scan_kernel(const int* __restrict__ deg, int* __restrict__ ioff) {
    __shared__ int part[256];
    int t = threadIdx.x;
    const int CH = (N_NODES + 255) / 256; // 40
    int base = t * CH;
    int s = 0;
    for (int j = 0; j < CH; ++j) {
        int idx = base + j;
        if (idx < N_NODES) s += deg[idx];
    }
    part[t] = s;
    __syncthreads();
    for (int o = 1; o < 256; o <<= 1) {
        int v = 0;
        if (t >= o) v = part[t - o];
        __syncthreads();
        part[t] += v;
        __syncthreads();
    }
    int run = (t == 0) ? 0 : part[t - 1];
    for (int j = 0; j < CH; ++j) {
        int idx = base + j;
        if (idx < N_NODES) { ioff[idx] = run; run += deg[idx]; }
    }
}

__global__ void scatter_kernel(const int* __restrict__ ei, int* __restrict__ ioff,
                               int* __restrict__ csr_src) {
    int tid = blockIdx.x * blockDim.x + threadIdx.x;
    if (tid >= ETOT) return;
    int src, dst;
    if (tid < E_EDGES) { src = ei[tid]; dst = ei[E_EDGES + tid]; }
    else { src = dst = tid - E_EDGES; }
    int pos = atomicAdd(&ioff[dst], 1);
    csr_src[pos] = src;
}

// ---------------- x -> fp16 ----------------
__global__ __launch_bounds__(256) void xconv_kernel(const float* __restrict__ in,
                                                    _Float16* __restrict__ o, int n4) {
    int i = blockIdx.x * blockDim.x + threadIdx.x;
    if (i >= n4) return;
    float4 v = ((const float4*)in)[i];
    half4 h = {(_Float16)v.x, (_Float16)v.y, (_Float16)v.z, (_Float16)v.w};
    ((half4*)o)[i] = h;
}

// W [k][n] fp32 -> Wt [n][k] fp16 (transposed); blockIdx.z = layer
__global__ __launch_bounds__(256) void wtconv_kernel(const float* __restrict__ Wall,
                                                     _Float16* __restrict__ t16all) {
    const float* W = Wall + (size_t)blockIdx.z * D_DIM * D_DIM;
    _Float16* t16 = t16all + (size_t)blockIdx.z * D_DIM * D_DIM;
    __shared__ float t[32][33];
    int bn = blockIdx.x * 32;
    int bk = blockIdx.y * 32;
    int tx = threadIdx.x & 31;
    int ty = threadIdx.x >> 5;
#pragma unroll
    for (int r = 0; r < 32; r += 8)
        t[ty + r][tx] = W[(size_t)(bk + ty + r) * D_DIM + bn + tx];
    __syncthreads();
#pragma unroll
    for (int r = 0; r < 32; r += 8)
        t16[(size_t)(bn + ty + r) * D_DIM + bk + tx] = (_Float16)t[tx][ty + r];
}

// ---------------- fp16 MFMA GEMM + fused attention-logit epilogue ----------------
// R8 configuration — best measured (58.2 us): 128x128 tile, 4 waves, dim3(8,79).
// R9 (64x128 staggered-m) and R10 (barrier-free wave-tiles) both regressed;
// R11's stats fusion broke BN self-consistency. This is the settled GEMM.
// Hout layout: head-major [8][N][128] (head = blockIdx.x).
__global__ __launch_bounds__(256) void gemm_mfma_kernel(const _Float16* __restrict__ A,
                                                        const _Float16* __restrict__ Bt,
                                                        _Float16* __restrict__ Hout,
                                                        const float* __restrict__ att_s,
                                                        const float* __restrict__ att_d,
                                                        float* __restrict__ asrc,
                                                        float* __restrict__ adst, int M) {
    __shared__ short As[128 * 32]; // [m][k] fp16 bits
    __shared__ short Bs[128 * 32]; // [n][k]
    __shared__ float sA[128], sD[128];
    int bm = blockIdx.y * 128;
    int bn = blockIdx.x * 128;
    int head = blockIdx.x;
    int tid = threadIdx.x;
    int wave = tid >> 6;
    int lane = tid & 63;
    int wm = (wave >> 1) * 64;
    int wn = (wave & 1) * 64;
    int quad = lane >> 4;
    int l16 = lane & 15;

    f32x4 acc[4][4];
#pragma unroll
    for (int i = 0; i < 4; ++i)
#pragma unroll
        for (int j = 0; j < 4; ++j) acc[i][j] = (f32x4){0.f, 0.f, 0.f, 0.f};

    int srow = lane >> 2;
    int scol = (lane & 3) * 16;

    for (int kb = 0; kb < 32; ++kb) {
        int k0 = kb * 32;
#pragma unroll
        for (int r = 0; r < 2; ++r) {
            int arow = wave * 16 + r * 64 + srow;
            int grow = bm + arow;
            if (grow > M - 1) grow = M - 1;
            const char* gp = (const char*)(A + (size_t)grow * 1024 + k0) + scol;
            __builtin_amdgcn_global_load_lds(
                (const __attribute__((address_space(1))) void*)gp,
                (__attribute__((address_space(3))) void*)((char*)As + (wave * 16 + r * 64) * 64),
                16, 0, 0);
        }
#pragma unroll
        for (int r = 0; r < 2; ++r) {
            int brow = wave * 16 + r * 64 + srow;
            const char* gp = (const char*)(Bt + (size_t)(bn + brow) * 1024 + k0) + scol;
            __builtin_amdgcn_global_load_lds(
                (const __attribute__((address_space(1))) void*)gp,
                (__attribute__((address_space(3))) void*)((char*)Bs + (wave * 16 + r * 64) * 64),
                16, 0, 0);
        }
        __syncthreads();

        half8 af[4], bfr[4];
#pragma unroll
        for (int i = 0; i < 4; ++i)
            af[i] = *(const half8*)(As + (wm + i * 16 + l16) * 32 + quad * 8);
#pragma unroll
        for (int j = 0; j < 4; ++j)
            bfr[j] = *(const half8*)(Bs + (wn + j * 16 + l16) * 32 + quad * 8);
#pragma unroll
        for (int i = 0; i < 4; ++i)
#pragma unroll
            for (int j = 0; j < 4; ++j)
                acc[i][j] = __builtin_amdgcn_mfma_f32_16x16x32_f16(af[i], bfr[j], acc[i][j], 0, 0, 0);
        __syncthreads();
    }

    // attention-logit partial dots over this wave's 64 cols
    float wsv[4], wdv[4];
#pragma unroll
    for (int j = 0; j < 4; ++j) {
        int c = wn + j * 16 + l16;
        wsv[j] = att_s[head * 128 + c];
        wdv[j] = att_d[head * 128 + c];
    }
    float psv[4][4], pdv[4][4];
#pragma unroll
    for (int i = 0; i < 4; ++i) {
#pragma unroll
        for (int reg = 0; reg < 4; ++reg) {
            float p = acc[i][0][reg] * wsv[0] + acc[i][1][reg] * wsv[1] +
                      acc[i][2][reg] * wsv[2] + acc[i][3][reg] * wsv[3];
            float q = acc[i][0][reg] * wdv[0] + acc[i][1][reg] * wdv[1] +
                      acc[i][2][reg] * wdv[2] + acc[i][3][reg] * wdv[3];
#pragma unroll
            for (int o = 1; o < 16; o <<= 1) {
                p += __shfl_xor(p, o);
                q += __shfl_xor(q, o);
            }
            psv[i][reg] = p;
            pdv[i][reg] = q;
        }
    }
    if ((wave & 1) == 0 && l16 == 0) {
#pragma unroll
        for (int i = 0; i < 4; ++i)
#pragma unroll
            for (int reg = 0; reg < 4; ++reg) {
                int r = wm + i * 16 + quad * 4 + reg;
                sA[r] = psv[i][reg];
                sD[r] = pdv[i][reg];
            }
    }
    // store h fp16, head-major: Hout[head][row][col128]
#pragma unroll
    for (int i = 0; i < 4; ++i) {
#pragma unroll
        for (int reg = 0; reg < 4; ++reg) {
            int gr = bm + wm + i * 16 + quad * 4 + reg;
            if (gr < M) {
                _Float16* hp = Hout + (size_t)head * N_NODES * 128 + (size_t)gr * 128 + wn + l16;
#pragma unroll
                for (int j = 0; j < 4; ++j) hp[j * 16] = (_Float16)acc[i][j][reg];
            }
        }
    }
    __syncthreads();
    if ((wave & 1) == 1 && l16 == 0) {
#pragma unroll
        for (int i = 0; i < 4; ++i)
#pragma unroll
            for (int reg = 0; reg < 4; ++reg) {
                int r = wm + i * 16 + quad * 4 + reg;
                int gr = bm + r;
                if (gr < M) {
                    asrc[gr * 8 + head] = sA[r] + psv[i][reg];
                    adst[gr * 8 + head] = sD[r] + pdv[i][reg];
                }
            }
    }
}

// ---------------- fused edge-softmax aggregation, head-partitioned ----------------
// head = bx&7 (XCD L2 affinity); h16 head-major [8][N][128]; edge loop x4
// unrolled (latency hiding). Subwarps retire independently — no terminal
// barrier (R11's fused-stats barrier cost ~2x agg time). Block 0 zeroes the
// bn-stats buffer (consumed only by later dispatches).
__global__ __launch_bounds__(256) void agg_kernel(const _Float16* __restrict__ h16,
                                                  const float* __restrict__ asrc,
                                                  const float* __restrict__ adst,
                                                  const int* __restrict__ ioff,
                                                  const int* __restrict__ csr_src,
                                                  const _Float16* __restrict__ prevh,
                                                  const float* __restrict__ bias,
                                                  _Float16* __restrict__ yout,
                                                  float* __restrict__ stats) {
    int bx = blockIdx.x;
    int tid = threadIdx.x;
    if (bx == 0) {
#pragma unroll
        for (int j = 0; j < 8; ++j) stats[tid + j * 256] = 0.f;
    }
    int head = bx & 7;
    int chunk = bx >> 3;
    int sub = tid >> 5;
    int lane = tid & 31;
    int n = chunk * 8 + sub;          // N=10000 divisible by 8
    int c4 = lane * 4;
    const _Float16* hh = h16 + (size_t)head * N_NODES * 128;
    int start = (n == 0) ? 0 : ioff[n - 1];
    int end = ioff[n];
    float ad = adst[n * 8 + head];
    float den = 0.f;
    float4 acc = make_float4(0.f, 0.f, 0.f, 0.f);
    int p = start;
    for (; p + 4 <= end; p += 4) {
        int s0 = csr_src[p + 0];
        int s1 = csr_src[p + 1];
        int s2 = csr_src[p + 2];
        int s3 = csr_src[p + 3];
        float a0 = asrc[s0 * 8 + head];
        float a1 = asrc[s1 * 8 + head];
        float a2 = asrc[s2 * 8 + head];
        float a3 = asrc[s3 * 8 + head];
        half4 h0 = *(const half4*)(hh + (size_t)s0 * 128 + c4);
        half4 h1 = *(const half4*)(hh + (size_t)s1 * 128 + c4);
        half4 h2 = *(const half4*)(hh + (size_t)s2 * 128 + c4);
        half4 h3 = *(const half4*)(hh + (size_t)s3 * 128 + c4);
        float e0 = a0 + ad; e0 = (e0 > 0.f) ? e0 : NEG_SLOPE * e0;
        float e1 = a1 + ad; e1 = (e1 > 0.f) ? e1 : NEG_SLOPE * e1;
        float e2 = a2 + ad; e2 = (e2 > 0.f) ? e2 : NEG_SLOPE * e2;
        float e3 = a3 + ad; e3 = (e3 > 0.f) ? e3 : NEG_SLOPE * e3;
        float x0 = __expf(e0), x1 = __expf(e1), x2 = __expf(e2), x3 = __expf(e3);
        den += (x0 + x1) + (x2 + x3);
        acc.x += x0 * (float)h0[0] + x1 * (float)h1[0] + x2 * (float)h2[0] + x3 * (float)h3[0];
        acc.y += x0 * (float)h0[1] + x1 * (float)h1[1] + x2 * (float)h2[1] + x3 * (float)h3[1];
        acc.z += x0 * (float)h0[2] + x1 * (float)h1[2] + x2 * (float)h2[2] + x3 * (float)h3[2];
        acc.w += x0 * (float)h0[3] + x1 * (float)h1[3] + x2 * (float)h2[3] + x3 * (float)h3[3];
    }
    for (; p < end; ++p) {
        int s = csr_src[p];
        float e = asrc[s * 8 + head] + ad;
        e = (e > 0.f) ? e : NEG_SLOPE * e;
        float ex = __expf(e);
        den += ex;
        half4 hv = *(const half4*)(hh + (size_t)s * 128 + c4);
        acc.x = fmaf(ex, (float)hv[0], acc.x);
        acc.y = fmaf(ex, (float)hv[1], acc.y);
        acc.z = fmaf(ex, (float)hv[2], acc.z);
        acc.w = fmaf(ex, (float)hv[3], acc.w);
    }
    float invd = 1.0f / den;
    int col = head * 128 + c4;
    half4 ph = *(const half4*)(prevh + (size_t)n * 1024 + col);
    float4 bv = *(const float4*)(bias + col);
    float r0 = fmaf(acc.x, invd, (float)ph[0] + bv.x);
    float r1 = fmaf(acc.y, invd, (float)ph[1] + bv.y);
    float r2 = fmaf(acc.z, invd, (float)ph[2] + bv.z);
    float r3 = fmaf(acc.w, invd, (float)ph[3] + bv.w);
    half4 o = {(_Float16)r0, (_Float16)r1, (_Float16)r2, (_Float16)r3};
    *(half4*)(yout + (size_t)n * 1024 + col) = o;
}

// ---------------- batchnorm (fp16 y) ----------------
// Stats MUST be computed from the same fp16-rounded y16 that bn_apply
// normalizes: for near-dead columns (var -> 0), x-mu must cancel exactly, or
// rsqrt(eps) amplifies fp16 rounding noise ~300x (R11's post-timing failure).
__global__ void bn_stats_kernel(const _Float16* __restrict__ y, float* __restrict__ stats) {
    int col = (blockIdx.x * 256 + threadIdx.x) * 2;  // grid.x = 2
    float s0 = 0.f, s1 = 0.f, q0 = 0.f, q1 = 0.f;
    for (int r = blockIdx.y; r < N_NODES; r += gridDim.y) {
        half2v v = *(const half2v*)(y + (size_t)r * 1024 + col);
        float a = (float)v[0], b = (float)v[1];
        s0 += a; q0 += a * a;
        s1 += b; q1 += b * b;
    }
    atomicAdd(&stats[col], s0);
    atomicAdd(&stats[col + 1], s1);
    atomicAdd(&stats[1024 + col], q0);
    atomicAdd(&stats[1024 + col + 1], q1);
}

// normalize+relu: y16 -> o16 (o is next layer's GEMM A / prev / pool input)
__global__ void bn_apply_kernel(const _Float16* __restrict__ y, const float* __restrict__ stats,
                                const float* __restrict__ gamma, const float* __restrict__ beta,
                                _Float16* __restrict__ oout) {
    int idx4 = blockIdx.x * blockDim.x + threadIdx.x;
    if (idx4 >= N_NODES * D_DIM / 4) return;
    int base = idx4 * 4;
    int col = base & 1023;
    const float invN = 1.0f / (float)N_NODES;
    half4 v = ((const half4*)y)[idx4];
    float r[4];
#pragma unroll
    for (int j = 0; j < 4; ++j) {
        int cc = col + j;
        float mu = stats[cc] * invN;
        float var = stats[1024 + cc] * invN - mu * mu;
        float t = ((float)v[j] - mu) * rsqrtf(var + BN_EPS) * gamma[cc] + beta[cc];
        r[j] = fmaxf(t, 0.f);
    }
    half4 h = {(_Float16)r[0], (_Float16)r[1], (_Float16)r[2], (_Float16)r[3]};
    ((half4*)oout)[idx4] = h;
}

// ---------------- pooling (atomic-free) + final linear ----------------
__global__ __launch_bounds__(256) void pool_kernel(const _Float16* __restrict__ h3,
                                                   const int* __restrict__ batch,
                                                   float* __restrict__ pooled) {
    int col = blockIdx.x * 256 + threadIdx.x;   // grid.x = 4
    int g = blockIdx.y;
    int lo = lower_bound_batch(batch, g);
    int hi = lower_bound_batch(batch, g + 1);
    float acc = 0.f;
    for (int r = lo; r < hi; ++r) acc += (float)h3[(size_t)r * 1024 + col];
    pooled[(size_t)g * 1024 + col] = acc;
}

__global__ void final_kernel(const float* __restrict__ pooled, const int* __restrict__ batch,
                             const float* __restrict__ Wout, const float* __restrict__ bout,
                             float* __restrict__ out) {
    int g = blockIdx.x;
    int t = threadIdx.x;
    float p0 = 0.f, p1 = 0.f;
    for (int d = t; d < 1024; d += 256) {
        float v = pooled[(size_t)g * 1024 + d];
        p0 = fmaf(v, Wout[2 * d], p0);
        p1 = fmaf(v, Wout[2 * d + 1], p1);
    }
    __shared__ float s0[256], s1[256];
    s0[t] = p0; s1[t] = p1;
    __syncthreads();
    for (int o = 128; o; o >>= 1) {
        if (t < o) { s0[t] += s0[t + o]; s1[t] += s1[t + o]; }
        __syncthreads();
    }
    if (t == 0) {
        int cnt = lower_bound_batch(batch, g + 1) - lower_bound_batch(batch, g);
        float inv = 1.0f / fmaxf((float)cnt, 1.0f);
        out[g * 2 + 0] = s0[0] * inv + bout[0];
        out[g * 2 + 1] = s1[0] * inv + bout[1];
    }
}

extern "C" void kernel_launch(void* const* d_in, const int* in_sizes, int n_in,
                              void* d_out, int out_size, void* d_ws, size_t ws_size,
                              hipStream_t stream) {
    const float* x        = (const float*)d_in[0];
    const int*   ei       = (const int*)d_in[1];
    const int*   batch    = (const int*)d_in[2];
    const float* W        = (const float*)d_in[3];
    const float* att_src  = (const float*)d_in[4];
    const float* att_dst  = (const float*)d_in[5];
    const float* att_bias = (const float*)d_in[6];
    const float* gamma    = (const float*)d_in[7];
    const float* beta     = (const float*)d_in[8];
    const float* Wout     = (const float*)d_in[9];
    const float* bout     = (const float*)d_in[10];
    float* out = (float*)d_out;

    const size_t ND = (size_t)N_NODES * D_DIM;
    float* ws = (float*)d_ws;
    float* asrc   = ws;                                  // N*H
    float* adst   = asrc + (size_t)N_NODES * H_HEADS;    // N*H
    float* stats  = adst + (size_t)N_NODES * H_HEADS;    // 2*D
    float* pooled = stats + 2 * D_DIM;                   // NG*D
    int* ideg     = (int*)(pooled + (size_t)NGRAPH * D_DIM); // N
    int* ioff     = ideg + N_NODES;                      // N
    int* csr_src  = ioff + N_NODES;                      // ETOT
    _Float16* bufP  = (_Float16*)(csr_src + ETOT);       // N*D: x16 -> o1 -> o2
    _Float16* bufO0 = bufP + ND;                         // N*D: o0
    _Float16* h16   = bufO0 + ND;                        // N*D: GEMM out, [8][N][128]
    _Float16* y16   = h16 + ND;                          // N*D: agg out (pre-BN)
    _Float16* Wt3   = y16 + ND;                          // 3*D*D fp16 (W^T)
    // total ≈ 93 MB

    hipMemsetAsync(ideg, 0, N_NODES * sizeof(int), stream);
    deg_kernel<<<(ETOT + 255) / 256, 256, 0, stream>>>(ei, ideg);
    scan_kernel<<<1, 256, 0, stream>>>(ideg, ioff);
    scatter_kernel<<<(ETOT + 255) / 256, 256, 0, stream>>>(ei, ioff, csr_src);
    xconv_kernel<<<(int)(ND / 4 + 255) / 256, 256, 0, stream>>>(x, bufP, (int)(ND / 4));
    wtconv_kernel<<<dim3(32, 32, 3), 256, 0, stream>>>(W, Wt3);

    // layer i: A = Ain[i]; prev = Pin[i] (all fp16); bn output -> Oout[i]
    const _Float16* Ain[3]  = {bufP, bufO0, bufP};
    const _Float16* Pin[3]  = {bufP, bufP, bufO0};
    _Float16* Oout[3]       = {bufO0, bufP, bufP};

    for (int i = 0; i < NBLK; ++i) {
        gemm_mfma_kernel<<<dim3(8, 79), 256, 0, stream>>>(
            Ain[i], Wt3 + (size_t)i * D_DIM * D_DIM, h16,
            att_src + i * H_HEADS * C_CH, att_dst + i * H_HEADS * C_CH,
            asrc, adst, N_NODES);
        agg_kernel<<<N_NODES, 256, 0, stream>>>(h16, asrc, adst, ioff, csr_src,
                                                Pin[i], att_bias + i * D_DIM, y16, stats);
        bn_stats_kernel<<<dim3(2, 128), 256, 0, stream>>>(y16, stats);
        bn_apply_kernel<<<(int)(ND / 4 + 255) / 256, 256, 0, stream>>>(
            y16, stats, gamma + i * D_DIM, beta + i * D_DIM, Oout[i]);
    }

    pool_kernel<<<dim3(4, NGRAPH), 256, 0, stream>>>(bufP, batch, pooled);
    final_kernel<<<NGRAPH, 256, 0, stream>>>(pooled, batch, Wout, bout, out);
}